// Round 2
// baseline (519.974 us; speedup 1.0000x reference)
//
#include <hip/hip_runtime.h>

// out[a,bc,d,g] = (1/3) * sum_{e,f} T1[a,bc,d,e,f] * T2[bc,e,f,g]
// A=4, BC=786432, slabs: 27 floats (T1/T2), 9 floats (out).
// HBM-bound: 425 MB read + 113 MB write -> ~85us floor at 6.3 TB/s.
// This version: async global->LDS staging (global_load_lds_dwordx4), no
// VGPR round-trip; waves issue 9 direct-to-LDS loads then hit the barrier.

#define BC_       786432
#define TILE_     64          // bc slabs per block
#define NTHREADS  256         // 4 a * 64 bc_local

// float4-unit strides
#define T1_A_STRIDE4   5308416   // BC_*27/4
#define OUT_A_STRIDE4  1769472   // BC_*9/4
#define T1_TILE4       432       // TILE_*27/4 per a-region
#define OUT_TILE4      144       // TILE_*9/4 per a-region

__device__ __forceinline__ void gld_lds16(const void* g, void* l) {
    __builtin_amdgcn_global_load_lds(
        (const __attribute__((address_space(1))) void*)g,
        (__attribute__((address_space(3))) void*)l,
        16, 0, 0);
}

__global__ __launch_bounds__(NTHREADS, 4)
void prod_einsum_kernel(const float* __restrict__ T1,
                        const float* __restrict__ T2,
                        float* __restrict__ Out) {
    // smem: [0,6912) T1 tile (4*64*27 f32), [6912,8640) T2 tile (64*27 f32).
    // Front 2304 floats reused as output staging after compute.
    __shared__ float smem[8640];
    float4* smem4 = (float4*)smem;

    const float4* T1v = (const float4*)T1;
    const float4* T2v = (const float4*)T2;
    float4* Outv = (float4*)Out;

    const int tid = threadIdx.x;
    const int blk = blockIdx.x;

    // ---- T1 staging: 1728 float4, direct to LDS. 6 full rounds + 192 tail.
    #pragma unroll
    for (int k = 0; k < 6; ++k) {
        int j = tid + k * 256;
        int a = j / 432;            // magic-mul, cheap
        int r = j - a * 432;
        gld_lds16(&T1v[a * T1_A_STRIDE4 + blk * T1_TILE4 + r], &smem4[j]);
    }
    if (tid < 192) {                // j = 1536..1727, all a=3
        int j = tid + 1536;
        gld_lds16(&T1v[3 * T1_A_STRIDE4 + blk * T1_TILE4 + (j - 1296)], &smem4[j]);
    }
    // ---- T2 staging: 432 float4 (256 + 176 tail; tail wave partial, lane0 live)
    gld_lds16(&T2v[blk * T1_TILE4 + tid], &smem4[1728 + tid]);
    if (tid < 176) {
        int j = tid + 256;
        gld_lds16(&T2v[blk * T1_TILE4 + j], &smem4[1728 + j]);
    }
    __syncthreads();   // compiler emits vmcnt(0) drain here — loads land in LDS

    // ---- Compute: thread = (a, bc_local); a uniform per wave ----
    const int a = tid >> 6;
    const int l = tid & 63;
    const float* t1 = smem + (a * TILE_ + l) * 27;   // stride 27: conflict-free
    const float* t2 = smem + 6912 + l * 27;

    float r1[27], r2[27];
    #pragma unroll
    for (int i = 0; i < 27; ++i) r1[i] = t1[i];
    #pragma unroll
    for (int i = 0; i < 27; ++i) r2[i] = t2[i];

    float acc[9];
    #pragma unroll
    for (int d = 0; d < 3; ++d) {
        #pragma unroll
        for (int g = 0; g < 3; ++g) {
            float s = 0.0f;
            #pragma unroll
            for (int e = 0; e < 3; ++e) {
                #pragma unroll
                for (int f = 0; f < 3; ++f) {
                    s += r1[d * 9 + e * 3 + f] * r2[e * 9 + f * 3 + g];
                }
            }
            acc[d * 3 + g] = s * (1.0f / 3.0f);
        }
    }

    __syncthreads();  // all LDS reads done; safe to overwrite front of smem

    // ---- Stage output: (a, l, 9) packed, stride 9: conflict-free ----
    #pragma unroll
    for (int i = 0; i < 9; ++i) {
        smem[(a * TILE_ + l) * 9 + i] = acc[i];
    }
    __syncthreads();

    // ---- Coalesced write: 4 regions of 144 float4 ----
    for (int j = tid; j < 4 * OUT_TILE4; j += NTHREADS) {
        int a2 = j / OUT_TILE4;
        int r = j - a2 * OUT_TILE4;
        Outv[a2 * OUT_A_STRIDE4 + blk * OUT_TILE4 + r] = smem4[j];
    }
}

extern "C" void kernel_launch(void* const* d_in, const int* in_sizes, int n_in,
                              void* d_out, int out_size, void* d_ws, size_t ws_size,
                              hipStream_t stream) {
    const float* T1 = (const float*)d_in[0];
    const float* T2 = (const float*)d_in[1];
    float* Out = (float*)d_out;
    prod_einsum_kernel<<<BC_ / TILE_, NTHREADS, 0, stream>>>(T1, T2, Out);
}